// Round 3
// baseline (30450.443 us; speedup 1.0000x reference)
//
#include <hip/hip_runtime.h>
#include <stdint.h>

typedef _Float16 f16x8 __attribute__((ext_vector_type(8)));
typedef float f32x4 __attribute__((ext_vector_type(4)));

static __device__ __forceinline__ float bf2f(unsigned short u) {
  return __uint_as_float(((unsigned int)u) << 16);
}
static __device__ __forceinline__ unsigned short f2bf(float f) {
  unsigned int u = __float_as_uint(f);
  u = (u + 0x7FFFu + ((u >> 16) & 1u)) >> 16;  // RNE
  return (unsigned short)u;
}
static __device__ __forceinline__ unsigned short f2h(float f) {
  _Float16 h = (_Float16)f;
  return __builtin_bit_cast(unsigned short, h);
}
static __device__ __forceinline__ float h2f(unsigned short b) {
  _Float16 h = __builtin_bit_cast(_Float16, b);
  return (float)h;
}
static __device__ __forceinline__ float sigm(float x) { return 1.0f / (1.0f + __expf(-x)); }

// ---------------- dtype probe: 1 = bf16 inputs, 0 = f32 inputs ----------------
__global__ void probe_kernel(const unsigned int* __restrict__ raw, unsigned int* __restrict__ dflag) {
  __shared__ int s;
  int tid = threadIdx.x;
  if (tid == 0) s = 0;
  __syncthreads();
  int v = 0;
  for (int k = 0; k < 4; ++k) {
    unsigned int d = raw[2048 + tid * 4 + k];
    unsigned int lo = d & 0xFFFFu, ex = (lo >> 7) & 0xFFu;
    if (lo == 0u || (ex >= 0x40u && ex <= 0x7Cu)) v++;
  }
  atomicAdd(&s, v);
  __syncthreads();
  if (tid == 0) dflag[0] = (s >= 614) ? 1u : 0u;
}

// ---------------- embedding -> f16 act0 [32768][448], pad cols -> 0 ----------
__global__ void embed_kernel(const int* __restrict__ x, const void* __restrict__ emb,
                             unsigned short* __restrict__ act, const unsigned int* __restrict__ dflag) {
  int idx = blockIdx.x * 256 + threadIdx.x;  // 32768 rows * 56 chunks
  int row = idx / 56, c = idx % 56;
  unsigned short* dst = act + (size_t)row * 448 + c * 8;
  union { uint4 v; unsigned short s[8]; } o;
  if (c < 50) {
    int tok = x[row];
    if (dflag[0]) {
      const unsigned short* e = (const unsigned short*)emb + (size_t)tok * 400 + c * 8;
      union { uint4 v; unsigned short s[8]; } r; r.v = *(const uint4*)e;
#pragma unroll
      for (int k = 0; k < 8; ++k) o.s[k] = f2h(bf2f(r.s[k]));
    } else {
      const float* e = (const float*)emb + (size_t)tok * 400 + c * 8;
      float4 r0 = *(const float4*)e, r1 = *(const float4*)(e + 4);
      const float* p0 = (const float*)&r0; const float* p1 = (const float*)&r1;
#pragma unroll
      for (int k = 0; k < 4; ++k) { o.s[k] = f2h(p0[k]); o.s[4 + k] = f2h(p1[k]); }
    }
  } else {
    o.v.x = o.v.y = o.v.z = o.v.w = 0u;
  }
  *(uint4*)dst = o.v;
}

// ---------------- weights/bias -> padded f16 layouts --------------------------
__global__ void prep_kernel(const void* __restrict__ wih, const void* __restrict__ whh,
                            const void* __restrict__ bih, const void* __restrict__ bhh,
                            unsigned short* __restrict__ WihP, unsigned short* __restrict__ WhhP,
                            float* __restrict__ biasP, int H, int Hp, int din, int dp,
                            const unsigned int* __restrict__ dflag) {
  int nb = 4 * Hp, bid = blockIdx.x, tid = threadIdx.x;
  bool isf32 = (dflag[0] == 0u);
  if (bid < 2 * nb) {
    bool ih = bid < nb;
    int j = ih ? bid : bid - nb;
    int q = j / Hp, i = j % Hp;
    int cdst = ih ? dp : Hp, csrc = ih ? din : H;
    unsigned short* dst = (ih ? WihP : WhhP) + (size_t)j * cdst;
    bool valid = i < H;
    const void* w = ih ? wih : whh;
    for (int m = tid; m < cdst; m += 256) {
      unsigned short v = 0;
      if (valid && m < csrc) {
        if (isf32) v = f2h(((const float*)w)[(size_t)(q * H + i) * csrc + m]);
        else       v = f2h(bf2f(((const unsigned short*)w)[(size_t)(q * H + i) * csrc + m]));
      }
      dst[m] = v;
    }
  } else {
    for (int m = tid; m < nb; m += 256) {
      int q = m / Hp, i = m % Hp;
      float v = 0.0f;
      if (i < H) {
        if (isf32) v = ((const float*)bih)[q * H + i] + ((const float*)bhh)[q * H + i];
        else       v = bf2f(((const unsigned short*)bih)[q * H + i]) + bf2f(((const unsigned short*)bhh)[q * H + i]);
      }
      biasP[m] = v;
    }
  }
}

// ---------------- final unpad: act3 f16 [.][448] -> d_out (bf16 or f32) -------
__global__ void unpad_kernel(const unsigned short* __restrict__ act, void* __restrict__ out,
                             const unsigned int* __restrict__ dflag) {
  int idx = blockIdx.x * 256 + threadIdx.x;  // 32768 * 50
  int row = idx / 50, c = idx % 50;
  const unsigned short* src = act + (size_t)row * 448 + c * 8;
  union { uint4 v; unsigned short s[8]; } u; u.v = *(const uint4*)src;
  if (dflag[0]) {
    union { uint4 v; unsigned short s[8]; } o;
#pragma unroll
    for (int k = 0; k < 8; ++k) o.s[k] = f2bf(h2f(u.s[k]));
    *(uint4*)((unsigned short*)out + (size_t)row * 400 + c * 8) = o.v;
  } else {
    float4 o0, o1;
    float* p0 = (float*)&o0; float* p1 = (float*)&o1;
#pragma unroll
    for (int k = 0; k < 4; ++k) { p0[k] = h2f(u.s[k]); p1[k] = h2f(u.s[4 + k]); }
    float* dst = (float*)out + (size_t)row * 400 + c * 8;
    *(float4*)dst = o0; *(float4*)(dst + 4) = o1;
  }
}

// ---------------- persistent per-layer LSTM (producer/consumer) ---------------
// Group g owns hidden units [4g, 4g+4) x 4 gates.
// Block g      (x-block): streams Gx(t) = x_t @ Wih^T into an 8-deep f32 ring.
// Block NG + g (h-block): recurrence; per-step wait via 8-way arrival counters.
template <int DP, int HP>
__global__ __launch_bounds__(256, 1) void lstm_kernel(
    const unsigned short* __restrict__ actIn, unsigned short* __restrict__ actOut,
    const unsigned short* __restrict__ WihP, const unsigned short* __restrict__ WhhP,
    const float* __restrict__ biasP, float* __restrict__ gx,
    unsigned int* __restrict__ flgx, unsigned int* __restrict__ flgh,
    unsigned int* __restrict__ cnt, int S) {
  constexpr int NG = HP / 4, NKX = DP / 32, NKH = HP / 32;
  constexpr unsigned PERQ = (unsigned)(NG / 8);  // arrivals per sub-counter per step
  extern __shared__ char smem[];
  const int tid = threadIdx.x, lane = tid & 63, wv = tid >> 6;
  const int kh = wv >> 1, mh = wv & 1;
  const int kc8 = (lane >> 4) << 3, lrow = lane & 15;
  const bool isx = (int)blockIdx.x < NG;
  const int g = isx ? blockIdx.x : blockIdx.x - NG;

  if (isx) {
    unsigned short* Bl = (unsigned short*)smem;            // NKX*512 f16
    float* Gp = (float*)(smem + (size_t)NKX * 1024);       // [2][64][16] f32
    for (int m = tid; m < NKX * 64; m += 256) {
      int ks = m >> 6, l = m & 63, col = l & 15;
      int kk = ks * 32 + ((l >> 4) << 3);
      int j = (col >> 2) * HP + g * 4 + (col & 3);
      *(f16x8*)(Bl + (size_t)m * 8) = *(const f16x8*)(WihP + (size_t)j * DP + kk);
    }
    __syncthreads();
    const int i4 = tid * 4;  // reduce cells [i4, i4+4)
    for (int t = 0; t < S; ++t) {
      if (t >= 7) {  // ring depth 8; stay <=6 ahead of consumer (tid0-only spin)
        if (tid == 0) {
          while (__hip_atomic_load(flgh + g, __ATOMIC_RELAXED, __HIP_MEMORY_SCOPE_AGENT) < (unsigned)(t - 6))
            __builtin_amdgcn_s_sleep(4);
        }
        __syncthreads();
      }
      f32x4 a0 = {0.f, 0.f, 0.f, 0.f}, a1 = {0.f, 0.f, 0.f, 0.f};
      const unsigned short* ap = actIn + ((size_t)t * 64 + mh * 32 + lrow) * DP + kc8;
#pragma unroll
      for (int k2 = 0; k2 < NKX / 2; ++k2) {
        int ksg = kh * (NKX / 2) + k2;
        f16x8 b = *(f16x8*)(Bl + ((size_t)ksg * 64 + lane) * 8);
        f16x8 x0 = *(const f16x8*)(ap + (size_t)ksg * 32);
        f16x8 x1 = *(const f16x8*)(ap + (size_t)16 * DP + ksg * 32);
        a0 = __builtin_amdgcn_mfma_f32_16x16x32_f16(x0, b, a0, 0, 0, 0);
        a1 = __builtin_amdgcn_mfma_f32_16x16x32_f16(x1, b, a1, 0, 0, 0);
      }
      {
        int br = (lane >> 4) * 4;
#pragma unroll
        for (int r = 0; r < 4; ++r) {
          Gp[(size_t)kh * 1024 + (mh * 32 + br + r) * 16 + lrow] = a0[r];
          Gp[(size_t)kh * 1024 + (mh * 32 + 16 + br + r) * 16 + lrow] = a1[r];
        }
      }
      __syncthreads();
      {
        float v0 = Gp[i4] + Gp[1024 + i4];
        float v1 = Gp[i4 + 1] + Gp[1024 + i4 + 1];
        float v2 = Gp[i4 + 2] + Gp[1024 + i4 + 2];
        float v3 = Gp[i4 + 3] + Gp[1024 + i4 + 3];
        float* cell = gx + ((size_t)g * 8 + (t & 7)) * 1024 + i4;
        unsigned long long p0 = ((unsigned long long)__float_as_uint(v1) << 32) | __float_as_uint(v0);
        unsigned long long p1 = ((unsigned long long)__float_as_uint(v3) << 32) | __float_as_uint(v2);
        __hip_atomic_store((unsigned long long*)cell, p0, __ATOMIC_RELAXED, __HIP_MEMORY_SCOPE_AGENT);
        __hip_atomic_store((unsigned long long*)(cell + 2), p1, __ATOMIC_RELAXED, __HIP_MEMORY_SCOPE_AGENT);
      }
      asm volatile("s_waitcnt vmcnt(0)" ::: "memory");
      __syncthreads();
      if (tid == 0)
        __hip_atomic_store(flgx + g, (unsigned)(t + 1), __ATOMIC_RELEASE, __HIP_MEMORY_SCOPE_AGENT);
    }
  } else {
    unsigned short* Bl = (unsigned short*)smem;            // NKH*512 f16
    float* Gp = (float*)(smem + (size_t)NKH * 1024);       // [2][64][16] f32
    for (int m = tid; m < NKH * 64; m += 256) {
      int ks = m >> 6, l = m & 63, col = l & 15;
      int kk = ks * 32 + ((l >> 4) << 3);
      int j = (col >> 2) * HP + g * 4 + (col & 3);
      *(f16x8*)(Bl + (size_t)m * 8) = *(const f16x8*)(WhhP + (size_t)j * HP + kk);
    }
    const int urow = tid >> 2, ui = tid & 3;
    const int unit = g * 4 + ui;
    const float bi = biasP[unit], bfb = biasP[HP + unit], bgb = biasP[2 * HP + unit], bob = biasP[3 * HP + unit];
    float creg = 0.0f;
    __syncthreads();
    for (int t = 0; t < S; ++t) {
      // wait: Gx(t) ready AND (t==0 or all NG arrivals for step t-1)
      {
        const unsigned need_c = PERQ * (unsigned)t;
        while (true) {
          int ok = 1;
          if (tid == 0)
            ok = (__hip_atomic_load(flgx + g, __ATOMIC_RELAXED, __HIP_MEMORY_SCOPE_AGENT) >= (unsigned)(t + 1));
          if (t > 0 && tid < 8)
            ok &= (__hip_atomic_load(cnt + tid * 32, __ATOMIC_RELAXED, __HIP_MEMORY_SCOPE_AGENT) >= need_c);
          if (__syncthreads_and(ok)) break;
          __builtin_amdgcn_s_sleep(2);
        }
        asm volatile("" ::: "memory");
      }
      // Gx cell (agent loads bypass stale caches on ring reuse)
      const float* gp = gx + ((size_t)g * 8 + (t & 7)) * 1024 + urow * 16 + ui;
      float gx0 = __hip_atomic_load(gp + 0, __ATOMIC_RELAXED, __HIP_MEMORY_SCOPE_AGENT);
      float gx1 = __hip_atomic_load(gp + 4, __ATOMIC_RELAXED, __HIP_MEMORY_SCOPE_AGENT);
      float gx2 = __hip_atomic_load(gp + 8, __ATOMIC_RELAXED, __HIP_MEMORY_SCOPE_AGENT);
      float gx3 = __hip_atomic_load(gp + 12, __ATOMIC_RELAXED, __HIP_MEMORY_SCOPE_AGENT);
      if (t > 0) {
        f32x4 a0 = {0.f, 0.f, 0.f, 0.f}, a1 = {0.f, 0.f, 0.f, 0.f};
        const unsigned short* hp = actOut + ((size_t)(t - 1) * 64 + mh * 32 + lrow) * HP + kc8;
#pragma unroll
        for (int k2 = 0; k2 < NKH / 2; ++k2) {
          int ksg = kh * (NKH / 2) + k2;
          f16x8 b = *(f16x8*)(Bl + ((size_t)ksg * 64 + lane) * 8);
          f16x8 h0 = *(const f16x8*)(hp + (size_t)ksg * 32);
          f16x8 h1 = *(const f16x8*)(hp + (size_t)16 * HP + ksg * 32);
          a0 = __builtin_amdgcn_mfma_f32_16x16x32_f16(h0, b, a0, 0, 0, 0);
          a1 = __builtin_amdgcn_mfma_f32_16x16x32_f16(h1, b, a1, 0, 0, 0);
        }
        int br = (lane >> 4) * 4;
#pragma unroll
        for (int r = 0; r < 4; ++r) {
          Gp[(size_t)kh * 1024 + (mh * 32 + br + r) * 16 + lrow] = a0[r];
          Gp[(size_t)kh * 1024 + (mh * 32 + 16 + br + r) * 16 + lrow] = a1[r];
        }
      }
      __syncthreads();
      float gi = gx0 + bi, gf = gx1 + bfb, gg = gx2 + bgb, go = gx3 + bob;
      if (t > 0) {
        int base = urow * 16 + ui;
        gi += Gp[base] + Gp[1024 + base];
        gf += Gp[base + 4] + Gp[1024 + base + 4];
        gg += Gp[base + 8] + Gp[1024 + base + 8];
        go += Gp[base + 12] + Gp[1024 + base + 12];
      }
      float ig = sigm(gi), fg = sigm(gf), gt = tanhf(gg), og = sigm(go);
      creg = fg * creg + ig * gt;
      float h = og * tanhf(creg);
      int hb = (int)f2h(h);
      int other = __shfl_xor(hb, 1);
      if ((ui & 1) == 0) {
        unsigned int pk = ((unsigned)hb & 0xFFFFu) | ((unsigned)other << 16);
        unsigned int* dst = (unsigned int*)(actOut + ((size_t)t * 64 + urow) * HP + g * 4 + ui);
        __hip_atomic_store(dst, pk, __ATOMIC_RELAXED, __HIP_MEMORY_SCOPE_AGENT);
      }
      asm volatile("s_waitcnt vmcnt(0)" ::: "memory");
      __syncthreads();
      if (tid == 0) {
        __hip_atomic_store(flgh + g, (unsigned)(t + 1), __ATOMIC_RELEASE, __HIP_MEMORY_SCOPE_AGENT);
        __hip_atomic_fetch_add(cnt + (g & 7) * 32, 1u, __ATOMIC_RELEASE, __HIP_MEMORY_SCOPE_AGENT);
      }
    }
  }
}

// ------------------------------- host ----------------------------------------
extern "C" void kernel_launch(void* const* d_in, const int* in_sizes, int n_in,
                              void* d_out, int out_size, void* d_ws, size_t ws_size,
                              hipStream_t stream) {
  (void)in_sizes; (void)n_in; (void)out_size; (void)ws_size;
  const int* x = (const int*)d_in[0];
  const void* emb = d_in[1];
  const void* wih[3] = {d_in[2], d_in[6], d_in[10]};
  const void* whh[3] = {d_in[3], d_in[7], d_in[11]};
  const void* bih[3] = {d_in[4], d_in[8], d_in[12]};
  const void* bhh[3] = {d_in[5], d_in[9], d_in[13]};

  char* ws = (char*)d_ws;
  size_t off = 0;
  unsigned short* act0 = (unsigned short*)(ws + off); off += (size_t)32768 * 448 * 2;
  unsigned short* act1 = (unsigned short*)(ws + off); off += (size_t)32768 * 1152 * 2;
  unsigned short* act2 = (unsigned short*)(ws + off); off += (size_t)32768 * 1152 * 2;
  unsigned short* act3 = (unsigned short*)(ws + off); off += (size_t)32768 * 448 * 2;
  unsigned short* WihP = (unsigned short*)(ws + off); off += (size_t)4608 * 1152 * 2;
  unsigned short* WhhP = (unsigned short*)(ws + off); off += (size_t)4608 * 1152 * 2;
  float* biasP = (float*)(ws + off); off += (size_t)4608 * 4;
  float* gx = (float*)(ws + off); off += (size_t)288 * 8 * 1024 * 4;
  unsigned int* flgx = (unsigned int*)(ws + off); off += 8192;  // flgx | flgh | cnt
  unsigned int* flgh = flgx + 512;
  unsigned int* cnt = flgx + 1024;   // 8 sub-counters, 128B apart
  unsigned int* dflag = (unsigned int*)(ws + off); off += 64;

  const size_t ldsz = 45056;  // max role LDS (36KB weights + 8KB Gp); no opt-in

  probe_kernel<<<1, 256, 0, stream>>>((const unsigned int*)emb, dflag);
  embed_kernel<<<7168, 256, 0, stream>>>(x, emb, act0, dflag);

  // Layer 0: 400(->448) -> 1150(->1152)
  prep_kernel<<<2 * 4608 + 1, 256, 0, stream>>>(wih[0], whh[0], bih[0], bhh[0],
                                                WihP, WhhP, biasP, 1150, 1152, 400, 448, dflag);
  hipMemsetAsync(flgx, 0, 8192, stream);
  lstm_kernel<448, 1152><<<576, 256, ldsz, stream>>>(act0, act1, WihP, WhhP, biasP, gx, flgx, flgh, cnt, 512);

  // Layer 1: 1150(->1152) -> 1150(->1152)
  prep_kernel<<<2 * 4608 + 1, 256, 0, stream>>>(wih[1], whh[1], bih[1], bhh[1],
                                                WihP, WhhP, biasP, 1150, 1152, 1150, 1152, dflag);
  hipMemsetAsync(flgx, 0, 8192, stream);
  lstm_kernel<1152, 1152><<<576, 256, ldsz, stream>>>(act1, act2, WihP, WhhP, biasP, gx, flgx, flgh, cnt, 512);

  // Layer 2: 1150(->1152) -> 400(->448)
  prep_kernel<<<2 * 1792 + 1, 256, 0, stream>>>(wih[2], whh[2], bih[2], bhh[2],
                                                WihP, WhhP, biasP, 400, 448, 1150, 1152, dflag);
  hipMemsetAsync(flgx, 0, 8192, stream);
  lstm_kernel<1152, 448><<<224, 256, ldsz, stream>>>(act2, act3, WihP, WhhP, biasP, gx, flgx, flgh, cnt, 512);

  unpad_kernel<<<6400, 256, 0, stream>>>(act3, d_out, dflag);
}

// Round 5
// 21973.679 us; speedup vs baseline: 1.3858x; 1.3858x over previous
//
#include <hip/hip_runtime.h>
#include <stdint.h>

typedef _Float16 f16x8 __attribute__((ext_vector_type(8)));
typedef _Float16 f16x4 __attribute__((ext_vector_type(4)));
typedef float f32x4 __attribute__((ext_vector_type(4)));

static __device__ __forceinline__ float bf2f(unsigned short u) {
  return __uint_as_float(((unsigned int)u) << 16);
}
static __device__ __forceinline__ unsigned short f2bf(float f) {
  unsigned int u = __float_as_uint(f);
  u = (u + 0x7FFFu + ((u >> 16) & 1u)) >> 16;  // RNE
  return (unsigned short)u;
}
static __device__ __forceinline__ unsigned short f2h(float f) {
  _Float16 h = (_Float16)f;
  return __builtin_bit_cast(unsigned short, h);
}
static __device__ __forceinline__ float h2f(unsigned short b) {
  _Float16 h = __builtin_bit_cast(_Float16, b);
  return (float)h;
}
static __device__ __forceinline__ float sigm(float x) { return 1.0f / (1.0f + __expf(-x)); }
static __device__ __forceinline__ float tanh_fast(float x) {
  float ax = fabsf(x);
  float e = __expf(-2.0f * ax);
  float r = (1.0f - e) / (1.0f + e);
  return copysignf(r, x);
}

// ---------------- dtype probe: 1 = bf16 inputs, 0 = f32 inputs ----------------
__global__ void probe_kernel(const unsigned int* __restrict__ raw, unsigned int* __restrict__ dflag) {
  __shared__ int s;
  int tid = threadIdx.x;
  if (tid == 0) s = 0;
  __syncthreads();
  int v = 0;
  for (int k = 0; k < 4; ++k) {
    unsigned int d = raw[2048 + tid * 4 + k];
    unsigned int lo = d & 0xFFFFu, ex = (lo >> 7) & 0xFFu;
    if (lo == 0u || (ex >= 0x40u && ex <= 0x7Cu)) v++;
  }
  atomicAdd(&s, v);
  __syncthreads();
  if (tid == 0) dflag[0] = (s >= 614) ? 1u : 0u;
}

// ---------------- embedding -> f16 act0 [32768][448], pad cols -> 0 ----------
__global__ void embed_kernel(const int* __restrict__ x, const void* __restrict__ emb,
                             unsigned short* __restrict__ act, const unsigned int* __restrict__ dflag) {
  int idx = blockIdx.x * 256 + threadIdx.x;  // 32768 rows * 56 chunks
  int row = idx / 56, c = idx % 56;
  unsigned short* dst = act + (size_t)row * 448 + c * 8;
  union { uint4 v; unsigned short s[8]; } o;
  if (c < 50) {
    int tok = x[row];
    if (dflag[0]) {
      const unsigned short* e = (const unsigned short*)emb + (size_t)tok * 400 + c * 8;
      union { uint4 v; unsigned short s[8]; } r; r.v = *(const uint4*)e;
#pragma unroll
      for (int k = 0; k < 8; ++k) o.s[k] = f2h(bf2f(r.s[k]));
    } else {
      const float* e = (const float*)emb + (size_t)tok * 400 + c * 8;
      float4 r0 = *(const float4*)e, r1 = *(const float4*)(e + 4);
      const float* p0 = (const float*)&r0; const float* p1 = (const float*)&r1;
#pragma unroll
      for (int k = 0; k < 4; ++k) { o.s[k] = f2h(p0[k]); o.s[4 + k] = f2h(p1[k]); }
    }
  } else {
    o.v.x = o.v.y = o.v.z = o.v.w = 0u;
  }
  *(uint4*)dst = o.v;
}

// ------------- weights/bias -> GROUP-MAJOR padded f16 layouts -----------------
// Row j' = g*16 + q*4 + u  <->  unit i = g*4+u, gate q (i,f,g,o).
__global__ void prep_kernel(const void* __restrict__ wih, const void* __restrict__ whh,
                            const void* __restrict__ bih, const void* __restrict__ bhh,
                            unsigned short* __restrict__ WihG, unsigned short* __restrict__ WhhG,
                            float* __restrict__ biasG, int H, int HPo, int din, int dpIn,
                            const unsigned int* __restrict__ dflag) {
  int nb = 4 * HPo, bid = blockIdx.x, tid = threadIdx.x;
  bool isf32 = (dflag[0] == 0u);
  if (bid < 2 * nb) {
    bool ih = bid < nb;
    int j = ih ? bid : bid - nb;
    int i = (j >> 4) * 4 + (j & 3), q = (j >> 2) & 3;
    int cdst = ih ? dpIn : HPo, csrc = ih ? din : H;
    unsigned short* dst = (ih ? WihG : WhhG) + (size_t)j * cdst;
    bool valid = i < H;
    const void* w = ih ? wih : whh;
    for (int m = tid; m < cdst; m += 256) {
      unsigned short v = 0;
      if (valid && m < csrc) {
        if (isf32) v = f2h(((const float*)w)[(size_t)(q * H + i) * csrc + m]);
        else       v = f2h(bf2f(((const unsigned short*)w)[(size_t)(q * H + i) * csrc + m]));
      }
      dst[m] = v;
    }
  } else {
    for (int m = tid; m < nb; m += 256) {
      int i = (m >> 4) * 4 + (m & 3), q = (m >> 2) & 3;
      float v = 0.0f;
      if (i < H) {
        if (isf32) v = ((const float*)bih)[q * H + i] + ((const float*)bhh)[q * H + i];
        else       v = bf2f(((const unsigned short*)bih)[q * H + i]) + bf2f(((const unsigned short*)bhh)[q * H + i]);
      }
      biasG[m] = v;
    }
  }
}

// ---------------- final unpad: act3 f16 [.][448] -> d_out (bf16 or f32) -------
__global__ void unpad_kernel(const unsigned short* __restrict__ act, void* __restrict__ out,
                             const unsigned int* __restrict__ dflag) {
  int idx = blockIdx.x * 256 + threadIdx.x;  // 32768 * 50
  int row = idx / 50, c = idx % 50;
  const unsigned short* src = act + (size_t)row * 448 + c * 8;
  union { uint4 v; unsigned short s[8]; } u; u.v = *(const uint4*)src;
  if (dflag[0]) {
    union { uint4 v; unsigned short s[8]; } o;
#pragma unroll
    for (int k = 0; k < 8; ++k) o.s[k] = f2bf(h2f(u.s[k]));
    *(uint4*)((unsigned short*)out + (size_t)row * 400 + c * 8) = o.v;
  } else {
    float4 o0, o1;
    float* p0 = (float*)&o0; float* p1 = (float*)&o1;
#pragma unroll
    for (int k = 0; k < 4; ++k) { p0[k] = h2f(u.s[k]); p1[k] = h2f(u.s[4 + k]); }
    float* dst = (float*)out + (size_t)row * 400 + c * 8;
    *(float4*)dst = o0; *(float4*)(dst + 4) = o1;
  }
}

// ------------- chunked GEMM: gx = act_chunk @ WihG^T, cell-layout f16 ---------
// A: [chrows][K] f16 (chunk), B: [N][K] f16 (group-major rows).
// gx[((size_t)g*chrows + m)*16 + u*4+q], g=n>>4, q=(n>>2)&3, u=n&3.
__global__ __launch_bounds__(256, 1) void gemm_xw_kernel(
    const unsigned short* __restrict__ A, const unsigned short* __restrict__ B,
    unsigned short* __restrict__ gx, int K, int chrows) {
  __shared__ unsigned short Asm[128 * 32], Bsm[128 * 32];  // 8KB each, XOR-swizzled
  const int tid = threadIdx.x, lane = tid & 63, wv = tid >> 6;
  const int bm0 = blockIdx.x * 128, bn0 = blockIdx.y * 128;
  f32x4 acc[2][8] = {};
  const int nkt = K >> 5;
  for (int kt = 0; kt < nkt; ++kt) {
    __syncthreads();
#pragma unroll
    for (int j = 0; j < 2; ++j) {
      int idx = tid * 2 + j, r = idx >> 2, c4 = idx & 3;
      uint4 va = *(const uint4*)(A + (size_t)(bm0 + r) * K + kt * 32 + c4 * 8);
      uint4 vb = *(const uint4*)(B + (size_t)(bn0 + r) * K + kt * 32 + c4 * 8);
      int off = (r * 64 + c4 * 16) ^ ((r & 7) << 4);
      *(uint4*)((char*)Asm + off) = va;
      *(uint4*)((char*)Bsm + off) = vb;
    }
    __syncthreads();
    f16x8 af[2], bf[8];
#pragma unroll
    for (int rt = 0; rt < 2; ++rt) {
      int arow = wv * 32 + rt * 16 + (lane & 15);
      int off = (arow * 64 + ((lane >> 4) << 4)) ^ ((arow & 7) << 4);
      af[rt] = *(const f16x8*)((char*)Asm + off);
    }
#pragma unroll
    for (int ct = 0; ct < 8; ++ct) {
      int brow = ct * 16 + (lane & 15);
      int off = (brow * 64 + ((lane >> 4) << 4)) ^ ((brow & 7) << 4);
      bf[ct] = *(const f16x8*)((char*)Bsm + off);
    }
#pragma unroll
    for (int rt = 0; rt < 2; ++rt)
#pragma unroll
      for (int ct = 0; ct < 8; ++ct)
        acc[rt][ct] = __builtin_amdgcn_mfma_f32_16x16x32_f16(af[rt], bf[ct], acc[rt][ct], 0, 0, 0);
  }
#pragma unroll
  for (int ct = 0; ct < 8; ++ct) {
    int n = bn0 + ct * 16 + (lane & 15);
    int g = n >> 4, w16 = n & 15;
    int cellcol = ((w16 & 3) << 2) | (w16 >> 2);
#pragma unroll
    for (int rt = 0; rt < 2; ++rt) {
#pragma unroll
      for (int reg = 0; reg < 4; ++reg) {
        int m = bm0 + wv * 32 + rt * 16 + ((lane >> 4) << 2) + reg;
        gx[((size_t)g * chrows + m) * 16 + cellcol] = f2h(acc[rt][ct][reg]);
      }
    }
  }
}

// ---------------- recurrent phase: h-part only, chunked ------------------------
// Block g owns hidden units [4g,4g+4) x 4 gates. MODE: 0=full, 1=sync-only diag,
// 2=compute-only diag (no waits).
template <int HP, int MODE>
static __device__ __forceinline__ void rec_body(
    const unsigned short* __restrict__ gxAll, unsigned short* __restrict__ actOut,
    const unsigned short* __restrict__ WhhG, const float* __restrict__ biasG,
    unsigned int* __restrict__ cnt, float* __restrict__ cstate,
    int t0, int TS, int chrows) {
  constexpr int NG = HP / 4, NKH = HP / 32, NK2 = NKH / 2;
  constexpr unsigned PERQ = (unsigned)(NG / 8);
  extern __shared__ char smem[];
  unsigned short* Bl = (unsigned short*)smem;             // NKH KB weight fragments
  float* Gp = (float*)(smem + (size_t)NKH * 1024);        // [2][64][16] f32 = 8KB
  const int tid = threadIdx.x, lane = tid & 63, wv = tid >> 6;
  const int kh = wv >> 1, mh = wv & 1;
  const int kc8 = (lane >> 4) << 3, lrow = lane & 15;
  const int g = blockIdx.x;
  const int urow = tid >> 2, ui = tid & 3;

  float b0 = 0.f, b1 = 0.f, b2 = 0.f, b3 = 0.f, creg = 0.0f;
  f16x4 gxv = {};
  if constexpr (MODE != 1) {
    for (int m = tid; m < NKH * 64; m += 256) {
      int ks = m >> 6, l = m & 63, col = l & 15;
      int kk = ks * 32 + ((l >> 4) << 3);
      *(f16x8*)(Bl + (size_t)m * 8) = *(const f16x8*)(WhhG + ((size_t)(g * 16 + col)) * HP + kk);
    }
    b0 = biasG[g * 16 + ui];
    b1 = biasG[g * 16 + 4 + ui];
    b2 = biasG[g * 16 + 8 + ui];
    b3 = biasG[g * 16 + 12 + ui];
    if (t0 > 0) creg = cstate[urow * HP + g * 4 + ui];
    gxv = *(const f16x4*)(gxAll + ((size_t)g * chrows + urow) * 16 + ui * 4);
  }
  __syncthreads();

  const int tend = t0 + TS;
  for (int t = t0; t < tend; ++t) {
    if constexpr (MODE != 2) {
      if (t > 0) {
        const unsigned need = PERQ * (unsigned)t;
        while (true) {
          int ok = 1;
          if (tid < 8)
            ok = (__hip_atomic_load(cnt + tid * 32, __ATOMIC_RELAXED, __HIP_MEMORY_SCOPE_AGENT) >= need);
          if (__syncthreads_and(ok)) break;
          __builtin_amdgcn_s_sleep(2);
        }
        asm volatile("" ::: "memory");
      }
    }
    if constexpr (MODE != 1) {
      if (t > 0) {
        f32x4 a0 = {0.f, 0.f, 0.f, 0.f}, a1 = {0.f, 0.f, 0.f, 0.f};
        const unsigned short* hp =
            actOut + ((size_t)(t - 1) * 64 + mh * 32 + lrow) * HP + kh * (NK2 * 32) + kc8;
        f16x8 hv0[NK2], hv1[NK2];
#pragma unroll
        for (int k2 = 0; k2 < NK2; ++k2) {
          hv0[k2] = *(const f16x8*)(hp + k2 * 32);
          hv1[k2] = *(const f16x8*)(hp + (size_t)16 * HP + k2 * 32);
        }
#pragma unroll
        for (int k2 = 0; k2 < NK2; ++k2) {
          f16x8 b = *(f16x8*)(Bl + ((size_t)(kh * NK2 + k2) * 64 + lane) * 8);
          a0 = __builtin_amdgcn_mfma_f32_16x16x32_f16(hv0[k2], b, a0, 0, 0, 0);
          a1 = __builtin_amdgcn_mfma_f32_16x16x32_f16(hv1[k2], b, a1, 0, 0, 0);
        }
        int br = (lane >> 4) * 4;
#pragma unroll
        for (int r = 0; r < 4; ++r) {
          Gp[(size_t)kh * 1024 + (mh * 32 + br + r) * 16 + lrow] = a0[r];
          Gp[(size_t)kh * 1024 + (mh * 32 + 16 + br + r) * 16 + lrow] = a1[r];
        }
      }
    }
    __syncthreads();
    unsigned short hb = 0;
    if constexpr (MODE != 1) {
      float gi = (float)gxv[0] + b0, gf = (float)gxv[1] + b1;
      float gg = (float)gxv[2] + b2, go = (float)gxv[3] + b3;
      if (t > 0) {
        int base = urow * 16 + ui;
        gi += Gp[base] + Gp[1024 + base];
        gf += Gp[base + 4] + Gp[1024 + base + 4];
        gg += Gp[base + 8] + Gp[1024 + base + 8];
        go += Gp[base + 12] + Gp[1024 + base + 12];
      }
      float ig = sigm(gi), fg = sigm(gf), gt = tanh_fast(gg), og = sigm(go);
      creg = fg * creg + ig * gt;
      hb = f2h(og * tanh_fast(creg));
    }
    int other = __shfl_xor((int)hb, 1);
    if ((ui & 1) == 0) {
      unsigned int pk = ((unsigned)hb & 0xFFFFu) | ((unsigned)other << 16);
      unsigned int* dst = (unsigned int*)(actOut + ((size_t)t * 64 + urow) * HP + g * 4 + ui);
      __hip_atomic_store(dst, pk, __ATOMIC_RELAXED, __HIP_MEMORY_SCOPE_AGENT);
    }
    asm volatile("s_waitcnt vmcnt(0)" ::: "memory");
    __syncthreads();
    if (tid == 0)
      __hip_atomic_fetch_add(cnt + (g & 7) * 32, 1u, __ATOMIC_RELEASE, __HIP_MEMORY_SCOPE_AGENT);
    if constexpr (MODE != 1) {
      if (t + 1 < tend)
        gxv = *(const f16x4*)(gxAll + ((size_t)g * chrows + (t + 1 - t0) * 64 + urow) * 16 + ui * 4);
    }
  }
  if constexpr (MODE != 1)
    cstate[urow * HP + g * 4 + ui] = creg;
}

__global__ __launch_bounds__(256, 1) void lstm_rec1152(
    const unsigned short* __restrict__ gxAll, unsigned short* __restrict__ actOut,
    const unsigned short* __restrict__ WhhG, const float* __restrict__ biasG,
    unsigned int* __restrict__ cnt, float* __restrict__ cstate, int t0, int TS, int chrows) {
  rec_body<1152, 0>(gxAll, actOut, WhhG, biasG, cnt, cstate, t0, TS, chrows);
}
__global__ __launch_bounds__(256, 1) void lstm_rec448(
    const unsigned short* __restrict__ gxAll, unsigned short* __restrict__ actOut,
    const unsigned short* __restrict__ WhhG, const float* __restrict__ biasG,
    unsigned int* __restrict__ cnt, float* __restrict__ cstate, int t0, int TS, int chrows) {
  rec_body<448, 0>(gxAll, actOut, WhhG, biasG, cnt, cstate, t0, TS, chrows);
}
__global__ __launch_bounds__(256, 1) void diag_sync_kernel(
    unsigned short* __restrict__ actD, unsigned int* __restrict__ cntD, int S) {
  rec_body<1152, 1>(nullptr, actD, nullptr, nullptr, cntD, nullptr, 0, S, 64 * S);
}
__global__ __launch_bounds__(256, 1) void diag_comp_kernel(
    const unsigned short* __restrict__ gxAll, unsigned short* __restrict__ actD,
    const unsigned short* __restrict__ WhhG, const float* __restrict__ biasG,
    unsigned int* __restrict__ cntD, float* __restrict__ cstate, int S, int chrows) {
  rec_body<1152, 2>(gxAll, actD, WhhG, biasG, cntD, cstate, 0, S, chrows);
}

// ------------------------------- host ----------------------------------------
extern "C" void kernel_launch(void* const* d_in, const int* in_sizes, int n_in,
                              void* d_out, int out_size, void* d_ws, size_t ws_size,
                              hipStream_t stream) {
  (void)in_sizes; (void)n_in; (void)out_size;
  const int* x = (const int*)d_in[0];
  const void* emb = d_in[1];
  const void* wih[3] = {d_in[2], d_in[6], d_in[10]};
  const void* whh[3] = {d_in[3], d_in[7], d_in[11]};
  const void* bih[3] = {d_in[4], d_in[8], d_in[12]};
  const void* bhh[3] = {d_in[5], d_in[9], d_in[13]};

  char* ws = (char*)d_ws;
  size_t off = 0;
  unsigned short* act0 = (unsigned short*)(ws + off); off += (size_t)32768 * 448 * 2;
  unsigned short* act1 = (unsigned short*)(ws + off); off += (size_t)32768 * 1152 * 2;
  unsigned short* act2 = (unsigned short*)(ws + off); off += (size_t)32768 * 1152 * 2;
  unsigned short* act3 = act0;  // alias: act0 dead after L0 GEMM chunks
  unsigned short* WihG = (unsigned short*)(ws + off); off += (size_t)4608 * 1152 * 2;
  unsigned short* WhhG = (unsigned short*)(ws + off); off += (size_t)4608 * 1152 * 2;
  float* biasG = (float*)(ws + off); off += (size_t)4608 * 4;
  float* cstate = (float*)(ws + off); off += (size_t)64 * 1152 * 4;
  unsigned int* cnt = (unsigned int*)(ws + off); off += 4096;
  unsigned int* cntD = (unsigned int*)(ws + off); off += 4096;
  unsigned int* dflag = (unsigned int*)(ws + off); off += 256;
  unsigned short* gx = (unsigned short*)(ws + off);
  unsigned short* actD = act1;  // diag scratch alias (act1 dead at diag time)

  // gx chunk sizing from remaining workspace (589,824 B per timestep)
  size_t avail = (ws_size > off) ? (ws_size - off) : 0;
  int CH = 512;
  while (CH > 32 && (size_t)CH * 589824 > avail) CH >>= 1;
  const int chrows = CH * 64, nch = 512 / CH;
  const int diagS = (CH < 64) ? CH : 64;

  probe_kernel<<<1, 256, 0, stream>>>((const unsigned int*)emb, dflag);
  embed_kernel<<<7168, 256, 0, stream>>>(x, emb, act0, dflag);

  // ---- Layer 0: din 400(->448) -> H 1150(->1152)
  prep_kernel<<<2 * 4608 + 1, 256, 0, stream>>>(wih[0], whh[0], bih[0], bhh[0],
                                                WihG, WhhG, biasG, 1150, 1152, 400, 448, dflag);
  hipMemsetAsync(cnt, 0, 4096, stream);
  for (int c = 0; c < nch; ++c) {
    gemm_xw_kernel<<<dim3(CH / 2, 36), 256, 0, stream>>>(act0 + (size_t)c * chrows * 448, WihG, gx, 448, chrows);
    lstm_rec1152<<<288, 256, 45056, stream>>>(gx, act1, WhhG, biasG, cnt, cstate, c * CH, CH, chrows);
  }

  // ---- Layer 1: 1150(->1152) -> 1150(->1152)
  prep_kernel<<<2 * 4608 + 1, 256, 0, stream>>>(wih[1], whh[1], bih[1], bhh[1],
                                                WihG, WhhG, biasG, 1150, 1152, 1150, 1152, dflag);
  hipMemsetAsync(cnt, 0, 4096, stream);
  for (int c = 0; c < nch; ++c) {
    gemm_xw_kernel<<<dim3(CH / 2, 36), 256, 0, stream>>>(act1 + (size_t)c * chrows * 1152, WihG, gx, 1152, chrows);
    lstm_rec1152<<<288, 256, 45056, stream>>>(gx, act2, WhhG, biasG, cnt, cstate, c * CH, CH, chrows);
  }

  // ---- Layer 2: 1150(->1152) -> H 400(->448)
  prep_kernel<<<2 * 1792 + 1, 256, 0, stream>>>(wih[2], whh[2], bih[2], bhh[2],
                                                WihG, WhhG, biasG, 400, 448, 1150, 1152, dflag);
  hipMemsetAsync(cnt, 0, 4096, stream);
  for (int c = 0; c < nch; ++c) {
    gemm_xw_kernel<<<dim3(CH / 2, 14), 256, 0, stream>>>(act2 + (size_t)c * chrows * 1152, WihG, gx, 1152, chrows);
    lstm_rec448<<<112, 256, 22528, stream>>>(gx, act3, WhhG, biasG, cnt, cstate, c * CH, CH, chrows);
  }

  unpad_kernel<<<6400, 256, 0, stream>>>(act3, d_out, dflag);

  // ---- diagnostics (scratch aliases; split sync-cost vs compute-cost) -------
  hipMemsetAsync(cntD, 0, 4096, stream);
  diag_sync_kernel<<<288, 256, 1024, stream>>>(actD, cntD, diagS);
  hipMemsetAsync(cntD, 0, 4096, stream);
  diag_comp_kernel<<<288, 256, 45056, stream>>>(gx, actD, WhhG, biasG, cntD, cstate, diagS, chrows);
}

// Round 6
// 18636.646 us; speedup vs baseline: 1.6339x; 1.1791x over previous
//
#include <hip/hip_runtime.h>
#include <stdint.h>

typedef _Float16 f16x8 __attribute__((ext_vector_type(8)));
typedef _Float16 f16x4 __attribute__((ext_vector_type(4)));
typedef float f32x4 __attribute__((ext_vector_type(4)));

static __device__ __forceinline__ float bf2f(unsigned short u) {
  return __uint_as_float(((unsigned int)u) << 16);
}
static __device__ __forceinline__ unsigned short f2bf(float f) {
  unsigned int u = __float_as_uint(f);
  u = (u + 0x7FFFu + ((u >> 16) & 1u)) >> 16;  // RNE
  return (unsigned short)u;
}
static __device__ __forceinline__ unsigned short f2h(float f) {
  _Float16 h = (_Float16)f;
  return __builtin_bit_cast(unsigned short, h);
}
static __device__ __forceinline__ float h2f(unsigned short b) {
  _Float16 h = __builtin_bit_cast(_Float16, b);
  return (float)h;
}
static __device__ __forceinline__ float sigm(float x) { return 1.0f / (1.0f + __expf(-x)); }
static __device__ __forceinline__ float tanh_fast(float x) {
  float ax = fabsf(x);
  float e = __expf(-2.0f * ax);
  float r = (1.0f - e) / (1.0f + e);
  return copysignf(r, x);
}

// ---------------- dtype probe: 1 = bf16 inputs, 0 = f32 inputs ----------------
__global__ void probe_kernel(const unsigned int* __restrict__ raw, unsigned int* __restrict__ dflag) {
  __shared__ int s;
  int tid = threadIdx.x;
  if (tid == 0) s = 0;
  __syncthreads();
  int v = 0;
  for (int k = 0; k < 4; ++k) {
    unsigned int d = raw[2048 + tid * 4 + k];
    unsigned int lo = d & 0xFFFFu, ex = (lo >> 7) & 0xFFu;
    if (lo == 0u || (ex >= 0x40u && ex <= 0x7Cu)) v++;
  }
  atomicAdd(&s, v);
  __syncthreads();
  if (tid == 0) dflag[0] = (s >= 614) ? 1u : 0u;
}

// ---------------- embedding -> f16 act0 [32768][448], pad cols -> 0 ----------
__global__ void embed_kernel(const int* __restrict__ x, const void* __restrict__ emb,
                             unsigned short* __restrict__ act, const unsigned int* __restrict__ dflag) {
  int idx = blockIdx.x * 256 + threadIdx.x;  // 32768 rows * 56 chunks
  int row = idx / 56, c = idx % 56;
  unsigned short* dst = act + (size_t)row * 448 + c * 8;
  union { uint4 v; unsigned short s[8]; } o;
  if (c < 50) {
    int tok = x[row];
    if (dflag[0]) {
      const unsigned short* e = (const unsigned short*)emb + (size_t)tok * 400 + c * 8;
      union { uint4 v; unsigned short s[8]; } r; r.v = *(const uint4*)e;
#pragma unroll
      for (int k = 0; k < 8; ++k) o.s[k] = f2h(bf2f(r.s[k]));
    } else {
      const float* e = (const float*)emb + (size_t)tok * 400 + c * 8;
      float4 r0 = *(const float4*)e, r1 = *(const float4*)(e + 4);
      const float* p0 = (const float*)&r0; const float* p1 = (const float*)&r1;
#pragma unroll
      for (int k = 0; k < 4; ++k) { o.s[k] = f2h(p0[k]); o.s[4 + k] = f2h(p1[k]); }
    }
  } else {
    o.v.x = o.v.y = o.v.z = o.v.w = 0u;
  }
  *(uint4*)dst = o.v;
}

// ------------- weights/bias -> GROUP-MAJOR padded f16 layouts -----------------
// Row j' = G*32 + q*8 + u  <->  unit i = G*8+u, gate q (i,f,g,o).
__global__ void prep_kernel(const void* __restrict__ wih, const void* __restrict__ whh,
                            const void* __restrict__ bih, const void* __restrict__ bhh,
                            unsigned short* __restrict__ WihG, unsigned short* __restrict__ WhhG,
                            float* __restrict__ biasG, int H, int HPo, int din, int dpIn,
                            const unsigned int* __restrict__ dflag) {
  int nb = 4 * HPo, bid = blockIdx.x, tid = threadIdx.x;
  bool isf32 = (dflag[0] == 0u);
  if (bid < 2 * nb) {
    bool ih = bid < nb;
    int j = ih ? bid : bid - nb;
    int i = (j >> 5) * 8 + (j & 7), q = (j >> 3) & 3;
    int cdst = ih ? dpIn : HPo, csrc = ih ? din : H;
    unsigned short* dst = (ih ? WihG : WhhG) + (size_t)j * cdst;
    bool valid = i < H;
    const void* w = ih ? wih : whh;
    for (int m = tid; m < cdst; m += 256) {
      unsigned short v = 0;
      if (valid && m < csrc) {
        if (isf32) v = f2h(((const float*)w)[(size_t)(q * H + i) * csrc + m]);
        else       v = f2h(bf2f(((const unsigned short*)w)[(size_t)(q * H + i) * csrc + m]));
      }
      dst[m] = v;
    }
  } else {
    for (int m = tid; m < nb; m += 256) {
      int i = (m >> 5) * 8 + (m & 7), q = (m >> 3) & 3;
      float v = 0.0f;
      if (i < H) {
        if (isf32) v = ((const float*)bih)[q * H + i] + ((const float*)bhh)[q * H + i];
        else       v = bf2f(((const unsigned short*)bih)[q * H + i]) + bf2f(((const unsigned short*)bhh)[q * H + i]);
      }
      biasG[m] = v;
    }
  }
}

// ---------------- final unpad: act3 f16 [.][448] -> d_out (bf16 or f32) -------
__global__ void unpad_kernel(const unsigned short* __restrict__ act, void* __restrict__ out,
                             const unsigned int* __restrict__ dflag) {
  int idx = blockIdx.x * 256 + threadIdx.x;  // 32768 * 50
  int row = idx / 50, c = idx % 50;
  const unsigned short* src = act + (size_t)row * 448 + c * 8;
  union { uint4 v; unsigned short s[8]; } u; u.v = *(const uint4*)src;
  if (dflag[0]) {
    union { uint4 v; unsigned short s[8]; } o;
#pragma unroll
    for (int k = 0; k < 8; ++k) o.s[k] = f2bf(h2f(u.s[k]));
    *(uint4*)((unsigned short*)out + (size_t)row * 400 + c * 8) = o.v;
  } else {
    float4 o0, o1;
    float* p0 = (float*)&o0; float* p1 = (float*)&o1;
#pragma unroll
    for (int k = 0; k < 4; ++k) { p0[k] = h2f(u.s[k]); p1[k] = h2f(u.s[4 + k]); }
    float* dst = (float*)out + (size_t)row * 400 + c * 8;
    *(float4*)dst = o0; *(float4*)(dst + 4) = o1;
  }
}

// ------------- chunked GEMM: gx = act_chunk @ WihG^T, cell-layout f16 ---------
// A: [chrows][K] f16 (chunk), B: [N][K] f16 (group-major rows).
// gx[((size_t)G*chrows + m)*32 + u*4 + q], G=n>>5, q=(n>>3)&3, u=n&7.
__global__ __launch_bounds__(256, 1) void gemm_xw_kernel(
    const unsigned short* __restrict__ A, const unsigned short* __restrict__ B,
    unsigned short* __restrict__ gx, int K, int chrows) {
  __shared__ unsigned short Asm[128 * 32], Bsm[128 * 32];  // 8KB each, XOR-swizzled
  const int tid = threadIdx.x, lane = tid & 63, wv = tid >> 6;
  const int bm0 = blockIdx.x * 128, bn0 = blockIdx.y * 128;
  f32x4 acc[2][8] = {};
  const int nkt = K >> 5;
  for (int kt = 0; kt < nkt; ++kt) {
    __syncthreads();
#pragma unroll
    for (int j = 0; j < 2; ++j) {
      int idx = tid * 2 + j, r = idx >> 2, c4 = idx & 3;
      uint4 va = *(const uint4*)(A + (size_t)(bm0 + r) * K + kt * 32 + c4 * 8);
      uint4 vb = *(const uint4*)(B + (size_t)(bn0 + r) * K + kt * 32 + c4 * 8);
      int off = (r * 64 + c4 * 16) ^ ((r & 7) << 4);
      *(uint4*)((char*)Asm + off) = va;
      *(uint4*)((char*)Bsm + off) = vb;
    }
    __syncthreads();
    f16x8 af[2], bf[8];
#pragma unroll
    for (int rt = 0; rt < 2; ++rt) {
      int arow = wv * 32 + rt * 16 + (lane & 15);
      int off = (arow * 64 + ((lane >> 4) << 4)) ^ ((arow & 7) << 4);
      af[rt] = *(const f16x8*)((char*)Asm + off);
    }
#pragma unroll
    for (int ct = 0; ct < 8; ++ct) {
      int brow = ct * 16 + (lane & 15);
      int off = (brow * 64 + ((lane >> 4) << 4)) ^ ((brow & 7) << 4);
      bf[ct] = *(const f16x8*)((char*)Bsm + off);
    }
#pragma unroll
    for (int rt = 0; rt < 2; ++rt)
#pragma unroll
      for (int ct = 0; ct < 8; ++ct)
        acc[rt][ct] = __builtin_amdgcn_mfma_f32_16x16x32_f16(af[rt], bf[ct], acc[rt][ct], 0, 0, 0);
  }
#pragma unroll
  for (int ct = 0; ct < 8; ++ct) {
    int n = bn0 + ct * 16 + (lane & 15);
    int G = n >> 5, c = n & 31;
    int cellcol = (c & 7) * 4 + (c >> 3);
#pragma unroll
    for (int rt = 0; rt < 2; ++rt) {
#pragma unroll
      for (int reg = 0; reg < 4; ++reg) {
        int m = bm0 + wv * 32 + rt * 16 + ((lane >> 4) << 2) + reg;
        gx[((size_t)G * chrows + m) * 32 + cellcol] = f2h(acc[rt][ct][reg]);
      }
    }
  }
}

// ---------------- recurrent phase: h-part only, chunked, weights in VGPR -------
// Block G owns 8 hidden units (32 gate-cols, group-major). 512 threads = 8 waves.
// Wave split: nq = wv&1 (16-col half), rr = wv>>1: MH==1 -> kq=rr (4 k-quarters);
// MH==2 -> kq=rr&1, mh=rr>>1 (k-halves x 32-row halves).
// MODE: 0=full, 1=sync-skeleton diag, 2=compute-only diag (no waits).
template <int HP, int KQ, int MH, int MODE>
static __device__ __forceinline__ void rec_body(
    const unsigned short* __restrict__ gxAll, unsigned short* __restrict__ actOut,
    const unsigned short* __restrict__ WhhG, const float* __restrict__ biasG,
    unsigned int* __restrict__ cnt, float* __restrict__ cstate,
    int t0, int TS, int chrows) {
  constexpr int NG = HP / 8;               // blocks
  constexpr unsigned PERQ = (unsigned)(NG / 8);
  constexpr int KS = HP / KQ;              // k per kq slice
  constexpr int KTPW = KS / 32;            // k-tiles per wave (9 or 7)
  constexpr int MT = 4 / MH;               // m-tiles per wave
  extern __shared__ char smem[];
  float* Gp = (float*)smem;                // [KQ][64][33] f32 padded
  const int tid = threadIdx.x, lane = tid & 63, wv = tid >> 6;
  const int nq = wv & 1, rr = wv >> 1;
  const int kq = (MH == 1) ? rr : (rr & (KQ - 1));
  const int mh = (MH == 1) ? 0 : (rr >> 1);
  const int lrow = lane & 15, kc8 = (lane >> 4) << 3;
  const int G = blockIdx.x;
  const int urow = tid >> 3, ui = tid & 7;  // reduce cell (row, unit)
  const int rmask = chrows - 1;             // chrows is a power of two * 64

  float b0 = 0.f, b1 = 0.f, b2 = 0.f, b3 = 0.f, creg = 0.0f;
  f16x8 wreg[KTPW];
  f16x4 gxv = {};
  if constexpr (MODE != 1) {
    const unsigned short* wp = WhhG + ((size_t)(G * 32 + nq * 16 + lrow)) * HP + kq * KS + kc8;
#pragma unroll
    for (int kt = 0; kt < KTPW; ++kt) wreg[kt] = *(const f16x8*)(wp + kt * 32);
    b0 = biasG[G * 32 + ui];
    b1 = biasG[G * 32 + 8 + ui];
    b2 = biasG[G * 32 + 16 + ui];
    b3 = biasG[G * 32 + 24 + ui];
    if (t0 > 0) creg = cstate[urow * HP + G * 8 + ui];
    gxv = *(const f16x4*)(gxAll + ((size_t)G * chrows + urow) * 32 + ui * 4);
  }
  __syncthreads();

  const int tend = t0 + TS;
  for (int t = t0; t < tend; ++t) {
    // ---- wait for all blocks' h(t-1)
    if constexpr (MODE != 2) {
      if (t > 0) {
        const unsigned need = PERQ * (unsigned)t;
        while (true) {
          int ok = 1;
          if (tid < 8)
            ok = (__hip_atomic_load(cnt + tid * 32, __ATOMIC_RELAXED, __HIP_MEMORY_SCOPE_AGENT) >= need);
          if (__syncthreads_and(ok)) break;
          __builtin_amdgcn_s_sleep(1);
        }
        asm volatile("" ::: "memory");
      }
    }
    // ---- h-part MFMA into Gp partials
    if constexpr (MODE != 1) {
      if (t > 0) {
#pragma unroll
        for (int m = 0; m < MT; ++m) {
          const int mt = mh * MT + m;
          f32x4 a = {0.f, 0.f, 0.f, 0.f};
          const unsigned short* hp =
              actOut + ((size_t)(t - 1) * 64 + mt * 16 + lrow) * HP + kq * KS + kc8;
          f16x8 hv[KTPW];
#pragma unroll
          for (int kt = 0; kt < KTPW; ++kt) hv[kt] = *(const f16x8*)(hp + kt * 32);
#pragma unroll
          for (int kt = 0; kt < KTPW; ++kt)
            a = __builtin_amdgcn_mfma_f32_16x16x32_f16(hv[kt], wreg[kt], a, 0, 0, 0);
          const int br = mt * 16 + (lane >> 4) * 4;
#pragma unroll
          for (int r = 0; r < 4; ++r)
            Gp[(kq * 64 + br + r) * 33 + nq * 16 + lrow] = a[r];
        }
      }
    }
    __syncthreads();
    // ---- reduce + gate update (one cell per thread)
    unsigned short hb = 0;
    if constexpr (MODE != 1) {
      float gi = (float)gxv[0] + b0, gf = (float)gxv[1] + b1;
      float gg = (float)gxv[2] + b2, go = (float)gxv[3] + b3;
      if (t > 0) {
#pragma unroll
        for (int k = 0; k < KQ; ++k) {
          const int base = (k * 64 + urow) * 33 + ui;
          gi += Gp[base];
          gf += Gp[base + 8];
          gg += Gp[base + 16];
          go += Gp[base + 24];
        }
      }
      float ig = sigm(gi), fg = sigm(gf), gt = tanh_fast(gg), og = sigm(go);
      creg = fg * creg + ig * gt;
      hb = f2h(og * tanh_fast(creg));
      if (t + 1 < tend)  // prefetch next gx cell (overlaps with publish)
        gxv = *(const f16x4*)(gxAll + ((size_t)G * chrows + (((t + 1 - t0) * 64 + urow) & rmask)) * 32 + ui * 4);
    }
    int other = __shfl_xor((int)hb, 1);
    if ((ui & 1) == 0) {
      unsigned int pk = ((unsigned)hb & 0xFFFFu) | ((unsigned)other << 16);
      unsigned int* dst = (unsigned int*)(actOut + ((size_t)t * 64 + urow) * HP + G * 8 + ui);
      __hip_atomic_store(dst, pk, __ATOMIC_RELAXED, __HIP_MEMORY_SCOPE_AGENT);
    }
    asm volatile("s_waitcnt vmcnt(0)" ::: "memory");
    __syncthreads();
    if (tid == 0)
      __hip_atomic_fetch_add(cnt + (G & 7) * 32, 1u, __ATOMIC_RELEASE, __HIP_MEMORY_SCOPE_AGENT);
  }
  if constexpr (MODE == 0)
    cstate[urow * HP + G * 8 + ui] = creg;
}

__global__ __launch_bounds__(512, 2) void lstm_rec1152(
    const unsigned short* __restrict__ gxAll, unsigned short* __restrict__ actOut,
    const unsigned short* __restrict__ WhhG, const float* __restrict__ biasG,
    unsigned int* __restrict__ cnt, float* __restrict__ cstate, int t0, int TS, int chrows) {
  rec_body<1152, 4, 1, 0>(gxAll, actOut, WhhG, biasG, cnt, cstate, t0, TS, chrows);
}
__global__ __launch_bounds__(512, 2) void lstm_rec448(
    const unsigned short* __restrict__ gxAll, unsigned short* __restrict__ actOut,
    const unsigned short* __restrict__ WhhG, const float* __restrict__ biasG,
    unsigned int* __restrict__ cnt, float* __restrict__ cstate, int t0, int TS, int chrows) {
  rec_body<448, 2, 2, 0>(gxAll, actOut, WhhG, biasG, cnt, cstate, t0, TS, chrows);
}
__global__ __launch_bounds__(512, 2) void diag_sync_kernel(
    unsigned short* __restrict__ actD, unsigned int* __restrict__ cntD, int S, int chrows) {
  rec_body<1152, 4, 1, 1>(nullptr, actD, nullptr, nullptr, cntD, nullptr, 0, S, chrows);
}
__global__ __launch_bounds__(512, 2) void diag_comp_kernel(
    const unsigned short* __restrict__ gxAll, unsigned short* __restrict__ actD,
    const unsigned short* __restrict__ WhhG, const float* __restrict__ biasG,
    unsigned int* __restrict__ cntD, int S, int chrows) {
  rec_body<1152, 4, 1, 2>(gxAll, actD, WhhG, biasG, cntD, nullptr, 0, S, chrows);
}

// ------------------------------- host ----------------------------------------
extern "C" void kernel_launch(void* const* d_in, const int* in_sizes, int n_in,
                              void* d_out, int out_size, void* d_ws, size_t ws_size,
                              hipStream_t stream) {
  (void)in_sizes; (void)n_in; (void)out_size;
  const int* x = (const int*)d_in[0];
  const void* emb = d_in[1];
  const void* wih[3] = {d_in[2], d_in[6], d_in[10]};
  const void* whh[3] = {d_in[3], d_in[7], d_in[11]};
  const void* bih[3] = {d_in[4], d_in[8], d_in[12]};
  const void* bhh[3] = {d_in[5], d_in[9], d_in[13]};

  char* ws = (char*)d_ws;
  size_t off = 0;
  unsigned short* act0 = (unsigned short*)(ws + off); off += (size_t)32768 * 448 * 2;
  unsigned short* act1 = (unsigned short*)(ws + off); off += (size_t)32768 * 1152 * 2;
  unsigned short* act2 = (unsigned short*)(ws + off); off += (size_t)32768 * 1152 * 2;
  unsigned short* act3 = act0;  // alias: act0 dead after L0 GEMM chunks
  unsigned short* WihG = (unsigned short*)(ws + off); off += (size_t)4608 * 1152 * 2;
  unsigned short* WhhG = (unsigned short*)(ws + off); off += (size_t)4608 * 1152 * 2;
  float* biasG = (float*)(ws + off); off += (size_t)4608 * 4;
  float* cstate = (float*)(ws + off); off += (size_t)64 * 1152 * 4;
  unsigned int* cnt = (unsigned int*)(ws + off); off += 4096;
  unsigned int* cntD = (unsigned int*)(ws + off); off += 4096;
  unsigned int* dflag = (unsigned int*)(ws + off); off += 256;
  unsigned short* gx = (unsigned short*)(ws + off);
  unsigned short* actD = act1;  // diag scratch alias (act1 dead at diag time)

  // gx chunk sizing from remaining workspace (589,824 B per timestep)
  size_t avail = (ws_size > off) ? (ws_size - off) : 0;
  int CH = 512;
  while (CH > 32 && (size_t)CH * 589824 > avail) CH >>= 1;
  const int chrows = CH * 64, nch = 512 / CH;
  const int diagS = 128;

  const size_t lds1152 = 4 * 64 * 33 * 4;  // 33,792 B
  const size_t lds448 = 2 * 64 * 33 * 4;   // 16,896 B

  probe_kernel<<<1, 256, 0, stream>>>((const unsigned int*)emb, dflag);
  embed_kernel<<<7168, 256, 0, stream>>>(x, emb, act0, dflag);

  // ---- Layer 0: din 400(->448) -> H 1150(->1152)
  prep_kernel<<<2 * 4608 + 1, 256, 0, stream>>>(wih[0], whh[0], bih[0], bhh[0],
                                                WihG, WhhG, biasG, 1150, 1152, 400, 448, dflag);
  hipMemsetAsync(cnt, 0, 4096, stream);
  for (int c = 0; c < nch; ++c) {
    gemm_xw_kernel<<<dim3(CH / 2, 36), 256, 0, stream>>>(act0 + (size_t)c * chrows * 448, WihG, gx, 448, chrows);
    lstm_rec1152<<<144, 512, lds1152, stream>>>(gx, act1, WhhG, biasG, cnt, cstate, c * CH, CH, chrows);
  }

  // ---- Layer 1: 1150(->1152) -> 1150(->1152)
  prep_kernel<<<2 * 4608 + 1, 256, 0, stream>>>(wih[1], whh[1], bih[1], bhh[1],
                                                WihG, WhhG, biasG, 1150, 1152, 1150, 1152, dflag);
  hipMemsetAsync(cnt, 0, 4096, stream);
  for (int c = 0; c < nch; ++c) {
    gemm_xw_kernel<<<dim3(CH / 2, 36), 256, 0, stream>>>(act1 + (size_t)c * chrows * 1152, WihG, gx, 1152, chrows);
    lstm_rec1152<<<144, 512, lds1152, stream>>>(gx, act2, WhhG, biasG, cnt, cstate, c * CH, CH, chrows);
  }

  // ---- Layer 2: 1150(->1152) -> H 400(->448)
  prep_kernel<<<2 * 1792 + 1, 256, 0, stream>>>(wih[2], whh[2], bih[2], bhh[2],
                                                WihG, WhhG, biasG, 400, 448, 1150, 1152, dflag);
  hipMemsetAsync(cnt, 0, 4096, stream);
  for (int c = 0; c < nch; ++c) {
    gemm_xw_kernel<<<dim3(CH / 2, 14), 256, 0, stream>>>(act2 + (size_t)c * chrows * 1152, WihG, gx, 1152, chrows);
    lstm_rec448<<<56, 512, lds448, stream>>>(gx, act3, WhhG, biasG, cnt, cstate, c * CH, CH, chrows);
  }

  unpad_kernel<<<6400, 256, 0, stream>>>(act3, d_out, dflag);

  // ---- diagnostics (scratch aliases; split sync-cost vs compute-cost) -------
  hipMemsetAsync(cntD, 0, 4096, stream);
  diag_sync_kernel<<<144, 512, lds1152, stream>>>(actD, cntD, diagS, chrows);
  hipMemsetAsync(cntD, 0, 4096, stream);
  diag_comp_kernel<<<144, 512, lds1152, stream>>>(gx, actD, WhhG, biasG, cntD, diagS, chrows);
}